// Round 5
// baseline (43.424 us; speedup 1.0000x reference)
//
#include <hip/hip_runtime.h>

// LSTM: B=65536, T=9, I=57, H=2 (4H=8 gates), fused single-pass kernel.
// 8 lanes per batch element. Cooperative dot: lane j loads x-slice {j, j+8,..},
// holds rotated weight slices, rotate-reduce puts gate j's sum on lane j.
//
// R3/R4 post-mortem: VGPR_Count=52 -> allocator rematerialized the 64
// loop-invariant wrot weights every timestep (~576 extra VMEM instrs/thread);
// latency-bound (VALUBusy 21.5%). Fixes here:
//   1. asm volatile "+v" pinning of wrot/whh/bsum -> remat impossible, must
//      stay register-resident.
//   2. double-buffered x prefetch (load t+1 before computing t) -> L3/HBM
//      latency hides under compute.
//   3. fast tanh via v_exp_f32 + v_rcp_f32 (~6 instrs vs ~30 for ocml tanhf);
//      exact saturation at +-inf, error ~1e-6 << 3.2e-3 threshold.

#define B_TOTAL 65536
#define T_STEPS 9
#define I_DIM   57

__device__ __forceinline__ float fast_tanh(float v) {
    // tanh(v) = 1 - 2/(exp(2v)+1);  exp(2v) = exp2(2*log2e*v)
    float e = __builtin_amdgcn_exp2f(2.885390082f * v);
    return 1.0f - 2.0f * __builtin_amdgcn_rcpf(e + 1.0f);
}

// One LSTM step: prefetch x row NT into NXT (if in range), compute with CUR.
// Fully macro-expanded so every register index is compile-time constant.
#define LSTM_STEP(CUR, NXT, NT) do {                                        \
    if ((NT) < T_STEPS) {                                                   \
        const float* xr_ = xb + (NT) * I_DIM;                               \
        _Pragma("unroll")                                                   \
        for (int k = 0; k < 7; ++k) NXT[k] = xr_[j + 8 * k];                \
        NXT[7] = xr_[56];                                                   \
    }                                                                       \
    float accv[8];                                                          \
    _Pragma("unroll")                                                       \
    for (int d = 0; d < 8; ++d) {                                           \
        float s_ = wrot[d][0] * CUR[0];                                     \
        _Pragma("unroll")                                                   \
        for (int k = 1; k < 8; ++k) s_ += wrot[d][k] * CUR[k];              \
        accv[d] = s_;                                                       \
    }                                                                       \
    float tot = accv[0];                                                    \
    _Pragma("unroll")                                                       \
    for (int d = 1; d < 8; ++d) tot += __shfl(accv[d], (j - d) & 7, 8);     \
    tot += bsum + h0 * whh0 + h1 * whh1;                                    \
    float y_ = fast_tanh(tanh_gate ? tot : 0.5f * tot);                     \
    float a_ = tanh_gate ? y_ : (0.5f * y_ + 0.5f);                         \
    float gi0 = __shfl(a_, 0, 8), gi1 = __shfl(a_, 1, 8);                   \
    float gf0 = __shfl(a_, 2, 8), gf1 = __shfl(a_, 3, 8);                   \
    float gg0 = __shfl(a_, 4, 8), gg1 = __shfl(a_, 5, 8);                   \
    float go0 = __shfl(a_, 6, 8), go1 = __shfl(a_, 7, 8);                   \
    c0 = gf0 * c0 + gi0 * gg0;                                              \
    c1 = gf1 * c1 + gi1 * gg1;                                              \
    h0 = go0 * fast_tanh(c0);                                               \
    h1 = go1 * fast_tanh(c1);                                               \
} while (0)

__global__ __launch_bounds__(256, 4)
void lstm_fused(const float* __restrict__ x,
                const float* __restrict__ W_ih,
                const float* __restrict__ W_hh,
                const float* __restrict__ b_ih,
                const float* __restrict__ b_hh,
                const float* __restrict__ fc_w,
                const float* __restrict__ fc_b,
                float* __restrict__ out) {
    const int lane = threadIdx.x & 63;   // lane within wave (wave = 64)
    const int wave = threadIdx.x >> 6;   // wave within block (4 waves)
    const int j    = lane & 7;           // lane within sub-group (gate owner)
    const int sg   = lane >> 3;          // sub-group (batch) within wave
    const int b    = blockIdx.x * 32 + wave * 8 + sg;
    if (b >= B_TOTAL) return;

    // Rotated weight slices: accv[d] accumulates gate (j+d)&7 over i-slice {j+8k}.
    float wrot[8][8];
#pragma unroll
    for (int d = 0; d < 8; ++d) {
        const int g = (j + d) & 7;
        const float* wr = W_ih + g * I_DIM;
#pragma unroll
        for (int k = 0; k < 7; ++k) wrot[d][k] = wr[j + 8 * k];
        wrot[d][7] = (j == 0) ? wr[56] : 0.0f;
    }

    float whh0 = W_hh[j * 2 + 0];
    float whh1 = W_hh[j * 2 + 1];
    float bsum = b_ih[j] + b_hh[j];
    const bool tanh_gate = ((j >> 1) == 2);   // gates 4,5 tanh, others sigmoid

    // Pin loop-invariants in VGPRs: opaque to the compiler -> cannot be
    // rematerialized from memory inside the t-loop.
#pragma unroll
    for (int d = 0; d < 8; ++d)
#pragma unroll
        for (int k = 0; k < 8; ++k)
            asm volatile("" : "+v"(wrot[d][k]));
    asm volatile("" : "+v"(whh0), "+v"(whh1), "+v"(bsum));

    float h0 = 0.f, h1 = 0.f, c0 = 0.f, c1 = 0.f;

    const float* xb = x + (size_t)b * (T_STEPS * I_DIM);

    // Prologue: load t=0 slice.
    float xva[8], xvb[8];
    {
        const float* xr_ = xb;
#pragma unroll
        for (int k = 0; k < 7; ++k) xva[k] = xr_[j + 8 * k];
        xva[7] = xr_[56];
    }

    LSTM_STEP(xva, xvb, 1);   // t=0, prefetch t=1
    LSTM_STEP(xvb, xva, 2);   // t=1, prefetch t=2
    LSTM_STEP(xva, xvb, 3);
    LSTM_STEP(xvb, xva, 4);
    LSTM_STEP(xva, xvb, 5);
    LSTM_STEP(xvb, xva, 6);
    LSTM_STEP(xva, xvb, 7);
    LSTM_STEP(xvb, xva, 8);
    LSTM_STEP(xva, xvb, 9);   // t=8, no prefetch

    if (j == 0) {
        out[b] = h0 * fc_w[0] + h1 * fc_w[1] + fc_b[0];
    }
}

extern "C" void kernel_launch(void* const* d_in, const int* in_sizes, int n_in,
                              void* d_out, int out_size, void* d_ws, size_t ws_size,
                              hipStream_t stream) {
    const float* x    = (const float*)d_in[0];
    const float* W_ih = (const float*)d_in[1];
    const float* W_hh = (const float*)d_in[2];
    const float* b_ih = (const float*)d_in[3];
    const float* b_hh = (const float*)d_in[4];
    const float* fc_w = (const float*)d_in[5];
    const float* fc_b = (const float*)d_in[6];
    float* out = (float*)d_out;

    // 32 batches per 256-thread block (8 lanes per batch) -> 2048 blocks.
    lstm_fused<<<dim3(B_TOTAL / 32), dim3(256), 0, stream>>>(
        x, W_ih, W_hh, b_ih, b_hh, fc_w, fc_b, out);
}

// Round 6
// 41.348 us; speedup vs baseline: 1.0502x; 1.0502x over previous
//
#include <hip/hip_runtime.h>

// LSTM B=65536, T=9, I=57, H=2 (4H=8) — two-pass restructure.
//
// R3-R5 post-mortem: fused kernel pinned at ~43us across three orthogonal
// micro-fixes -> structural limit: one wave-generation (8192 waves, no churn),
// 9 serial steps x 15 ds_bpermute + 8-segment loads per step.
//
// Pass 1 (lstm_gx): gx[t][b][j] = b_ih[j]+b_hh[j] + dot(W_ih[j], x[b,t]) for
//   all 589824 rows. Independent rows -> 16 rows per 8-lane group, 36864
//   groups, wave churn, 7 shuffles/row. Streams x at memory floor.
//   Transposed [T][B][8] layout -> pass-2 loads perfectly coalesced.
// Pass 2 (lstm_rec): 1 thread/batch, 9-step recurrence on L2/L3-hot gx,
//   zero cross-lane ops, all waves co-resident (~2-5us).

#define B_TOTAL 65536
#define T_STEPS 9
#define I_DIM   57
#define NROWS   (B_TOTAL * T_STEPS)      // 589824
#define P1_BLOCKS 1152
#define NGROUPS  (P1_BLOCKS * 32)        // 36864 8-lane groups
#define ROWS_PER_GROUP (NROWS / NGROUPS) // 16 exactly

__device__ __forceinline__ float fast_tanh(float v) {
    // tanh(v) = 1 - 2/(exp(2v)+1); exp(2v) = exp2(2*log2e*v). Err ~1e-6.
    float e = __builtin_amdgcn_exp2f(2.885390082f * v);
    return 1.0f - 2.0f * __builtin_amdgcn_rcpf(e + 1.0f);
}
__device__ __forceinline__ float fast_sig(float v) {
    return 0.5f * fast_tanh(0.5f * v) + 0.5f;
}

// ---------------- Pass 1: gx precompute ----------------

#define LOADX(BUF, R) do {                                                  \
    const float* xr_ = x + (size_t)(R) * I_DIM;                             \
    _Pragma("unroll")                                                       \
    for (int k = 0; k < 7; ++k) BUF[k] = xr_[j + 8 * k];                    \
    BUF[7] = xr_[56];  /* broadcast; pairs with wrot[d][7] (lane 0 only) */ \
} while (0)

#define PROCESS(BUF, R) do {                                                \
    float acc_[8];                                                          \
    _Pragma("unroll")                                                       \
    for (int d = 0; d < 8; ++d) {                                           \
        float s_ = wrot[d][0] * BUF[0];                                     \
        _Pragma("unroll")                                                   \
        for (int k = 1; k < 8; ++k) s_ += wrot[d][k] * BUF[k];              \
        acc_[d] = s_;                                                       \
    }                                                                       \
    float tot_ = acc_[0];                                                   \
    _Pragma("unroll")                                                       \
    for (int d = 1; d < 8; ++d) tot_ += __shfl(acc_[d], (j - d) & 7, 8);    \
    tot_ += bsum;                                                           \
    const int r_ = (R);                                                     \
    const int b_ = r_ / T_STEPS;                                            \
    const int t_ = r_ - b_ * T_STEPS;                                       \
    gxT[((size_t)t_ * B_TOTAL + b_) * 8 + j] = tot_;                        \
} while (0)

__global__ __launch_bounds__(256, 2)
void lstm_gx(const float* __restrict__ x,
             const float* __restrict__ W_ih,
             const float* __restrict__ b_ih,
             const float* __restrict__ b_hh,
             float* __restrict__ gxT) {
    const int lane = threadIdx.x & 63;
    const int j    = lane & 7;                                   // gate lane
    const int grp  = (blockIdx.x * 256 + threadIdx.x) >> 3;      // 0..36863

    // Rotated weight slices (validated in R3, absmax 0.0).
    float wrot[8][8];
#pragma unroll
    for (int d = 0; d < 8; ++d) {
        const int g = (j + d) & 7;
        const float* wr = W_ih + g * I_DIM;
#pragma unroll
        for (int k = 0; k < 7; ++k) wrot[d][k] = wr[j + 8 * k];
        wrot[d][7] = (j == 0) ? wr[56] : 0.0f;
    }
    float bsum = b_ih[j] + b_hh[j];
#pragma unroll
    for (int d = 0; d < 8; ++d)
#pragma unroll
        for (int k = 0; k < 8; ++k)
            asm volatile("" : "+v"(wrot[d][k]));

#define ROW(IT) ((IT) * NGROUPS + grp)

    float xa[8], xb[8];
    LOADX(xa, ROW(0));
#pragma unroll
    for (int it = 0; it < ROWS_PER_GROUP; it += 2) {
        if (it + 1 < ROWS_PER_GROUP) LOADX(xb, ROW(it + 1));
        PROCESS(xa, ROW(it));
        if (it + 2 < ROWS_PER_GROUP) LOADX(xa, ROW(it + 2));
        if (it + 1 < ROWS_PER_GROUP) PROCESS(xb, ROW(it + 1));
    }
#undef ROW
}

// ---------------- Pass 2: recurrence ----------------

__global__ __launch_bounds__(256, 2)
void lstm_rec(const float* __restrict__ gxT,
              const float* __restrict__ W_hh,
              const float* __restrict__ fc_w,
              const float* __restrict__ fc_b,
              float* __restrict__ out) {
    const int b = blockIdx.x * 256 + threadIdx.x;

    float w0[8], w1[8];
#pragma unroll
    for (int g = 0; g < 8; ++g) { w0[g] = W_hh[g * 2]; w1[g] = W_hh[g * 2 + 1]; }

    float h0 = 0.f, h1 = 0.f, c0 = 0.f, c1 = 0.f;

    const float* gb0 = gxT + (size_t)b * 8;
    float4 ga = *(const float4*)(gb0);
    float4 gbv = *(const float4*)(gb0 + 4);

#pragma unroll
    for (int t = 0; t < T_STEPS; ++t) {
        float4 na, nb;
        if (t + 1 < T_STEPS) {
            const float* p = gxT + ((size_t)(t + 1) * B_TOTAL + b) * 8;
            na = *(const float4*)(p);
            nb = *(const float4*)(p + 4);
        }
        // gate order i,f,g,o over 8 rows [i0,i1,f0,f1,g0,g1,o0,o1]
        const float i0 = fast_sig (ga.x + h0 * w0[0] + h1 * w1[0]);
        const float i1 = fast_sig (ga.y + h0 * w0[1] + h1 * w1[1]);
        const float f0 = fast_sig (ga.z + h0 * w0[2] + h1 * w1[2]);
        const float f1 = fast_sig (ga.w + h0 * w0[3] + h1 * w1[3]);
        const float g0 = fast_tanh(gbv.x + h0 * w0[4] + h1 * w1[4]);
        const float g1 = fast_tanh(gbv.y + h0 * w0[5] + h1 * w1[5]);
        const float o0 = fast_sig (gbv.z + h0 * w0[6] + h1 * w1[6]);
        const float o1 = fast_sig (gbv.w + h0 * w0[7] + h1 * w1[7]);
        c0 = f0 * c0 + i0 * g0;
        c1 = f1 * c1 + i1 * g1;
        h0 = o0 * fast_tanh(c0);
        h1 = o1 * fast_tanh(c1);
        if (t + 1 < T_STEPS) { ga = na; gbv = nb; }
    }

    out[b] = h0 * fc_w[0] + h1 * fc_w[1] + fc_b[0];
}

extern "C" void kernel_launch(void* const* d_in, const int* in_sizes, int n_in,
                              void* d_out, int out_size, void* d_ws, size_t ws_size,
                              hipStream_t stream) {
    const float* x    = (const float*)d_in[0];
    const float* W_ih = (const float*)d_in[1];
    const float* W_hh = (const float*)d_in[2];
    const float* b_ih = (const float*)d_in[3];
    const float* b_hh = (const float*)d_in[4];
    const float* fc_w = (const float*)d_in[5];
    const float* fc_b = (const float*)d_in[6];
    float* out = (float*)d_out;
    float* gxT = (float*)d_ws;   // needs NROWS*8*4 = 18.9 MB << ws_size

    lstm_gx<<<dim3(P1_BLOCKS), dim3(256), 0, stream>>>(x, W_ih, b_ih, b_hh, gxT);
    lstm_rec<<<dim3(B_TOTAL / 256), dim3(256), 0, stream>>>(gxT, W_hh, fc_w, fc_b, out);
}